// Round 8
// baseline (356.028 us; speedup 1.0000x reference)
//
#include <hip/hip_runtime.h>
#include <math.h>

#define NNODES 50000
#define D 256
#define NSAMP 5
#define LN_EPS 1e-5f
#define ELLW 96          // max degree capacity; Poisson(32) => P(row overflow) ~ 4e-20
#define EPT 8            // edges per build thread

typedef __bf16 bf16;
typedef __attribute__((ext_vector_type(8))) __bf16 bf16x8;
typedef __attribute__((ext_vector_type(4))) float f32x4;

__device__ inline float bflo(unsigned int u) { return __uint_as_float(u << 16); }
__device__ inline float bfhi(unsigned int u) { return __uint_as_float(u & 0xffff0000u); }

__device__ inline unsigned long long packcv(int c, float v) {
    return (unsigned long long)(unsigned int)c |
           ((unsigned long long)(unsigned int)__float_as_uint(v) << 32);
}

// ---------------------------------------------------------------------------
// K0: blocks 0..255: wt[n][k] = bf16(w[k][n]); blocks 256+: zero cnt
// ---------------------------------------------------------------------------
__global__ void prep_kernel(const float* __restrict__ w, bf16* __restrict__ wt,
                            int* __restrict__ cnt) {
    const int b = blockIdx.x;
    if (b < D) {
        const int k = threadIdx.x;
        wt[(size_t)b * D + k] = (bf16)w[(size_t)k * D + b];
    } else {
        const int i = (b - D) * 256 + threadIdx.x;
        if (i < NNODES) cnt[i] = 0;
    }
}

// ---------------------------------------------------------------------------
// K1 (fused dispatch): blocks [0, EB): single-pass ELL build (long pole first)
//                      blocks [EB, EB+GB): GEMM h = x @ w via MFMA
// Build: 8 edges/thread — batched loads, 8 independent atomics, 8 nt stores.
// ---------------------------------------------------------------------------
__global__ __launch_bounds__(256) void gemm_build_kernel(const float* __restrict__ x,
                                                         const bf16* __restrict__ wt,
                                                         bf16* __restrict__ h,
                                                         const int* __restrict__ rows,
                                                         const int* __restrict__ cols,
                                                         const float* __restrict__ vals,
                                                         int* __restrict__ cnt,
                                                         unsigned long long* __restrict__ ep,
                                                         int EB, int E) {
    if ((int)blockIdx.x < EB) {
        const int e0 = (blockIdx.x * 256 + threadIdx.x) * EPT;
        if (e0 + EPT - 1 < E) {
            const int4   ra = *(const int4*)(rows + e0);
            const int4   rb = *(const int4*)(rows + e0 + 4);
            const int4   ca = *(const int4*)(cols + e0);
            const int4   cb = *(const int4*)(cols + e0 + 4);
            const float4 va = *(const float4*)(vals + e0);
            const float4 vb = *(const float4*)(vals + e0 + 4);
            // 8 independent atomic rank grabs
            const int k0 = atomicAdd(&cnt[ra.x], 1);
            const int k1 = atomicAdd(&cnt[ra.y], 1);
            const int k2 = atomicAdd(&cnt[ra.z], 1);
            const int k3 = atomicAdd(&cnt[ra.w], 1);
            const int k4 = atomicAdd(&cnt[rb.x], 1);
            const int k5 = atomicAdd(&cnt[rb.y], 1);
            const int k6 = atomicAdd(&cnt[rb.z], 1);
            const int k7 = atomicAdd(&cnt[rb.w], 1);
            // 8 independent nontemporal scattered 8B stores (write-once data)
            if (k0 < ELLW) __builtin_nontemporal_store(packcv(ca.x, va.x), &ep[(size_t)ra.x * ELLW + k0]);
            if (k1 < ELLW) __builtin_nontemporal_store(packcv(ca.y, va.y), &ep[(size_t)ra.y * ELLW + k1]);
            if (k2 < ELLW) __builtin_nontemporal_store(packcv(ca.z, va.z), &ep[(size_t)ra.z * ELLW + k2]);
            if (k3 < ELLW) __builtin_nontemporal_store(packcv(ca.w, va.w), &ep[(size_t)ra.w * ELLW + k3]);
            if (k4 < ELLW) __builtin_nontemporal_store(packcv(cb.x, vb.x), &ep[(size_t)rb.x * ELLW + k4]);
            if (k5 < ELLW) __builtin_nontemporal_store(packcv(cb.y, vb.y), &ep[(size_t)rb.y * ELLW + k5]);
            if (k6 < ELLW) __builtin_nontemporal_store(packcv(cb.z, vb.z), &ep[(size_t)rb.z * ELLW + k6]);
            if (k7 < ELLW) __builtin_nontemporal_store(packcv(cb.w, vb.w), &ep[(size_t)rb.w * ELLW + k7]);
        } else {
            for (int e = e0; e < E; ++e) {
                const int r = rows[e];
                const int k = atomicAdd(&cnt[r], 1);
                if (k < ELLW) ep[(size_t)r * ELLW + k] = packcv(cols[e], vals[e]);
            }
        }
        return;
    }

    // ---- GEMM path (identical to validated round-2 kernel) ----
    const int gb = blockIdx.x - EB;
    const int wave = threadIdx.x >> 6;
    const int lane = threadIdx.x & 63;
    const int row0 = gb * 64 + wave * 16;
    const int am = lane & 15;
    const int ag = lane >> 4;

    int arow = row0 + am;
    if (arow >= NNODES) arow = NNODES - 1;

    f32x4 acc[16];
#pragma unroll
    for (int n = 0; n < 16; ++n) acc[n] = (f32x4){0.f, 0.f, 0.f, 0.f};

#pragma unroll
    for (int kk = 0; kk < 8; ++kk) {
        const int kb = kk * 32 + ag * 8;
        const float* xp = x + (size_t)arow * D + kb;
        const f32x4 a0 = __builtin_nontemporal_load((const f32x4*)xp);
        const f32x4 a1 = __builtin_nontemporal_load((const f32x4*)(xp + 4));
        bf16x8 a;
        a[0] = (bf16)a0[0]; a[1] = (bf16)a0[1]; a[2] = (bf16)a0[2]; a[3] = (bf16)a0[3];
        a[4] = (bf16)a1[0]; a[5] = (bf16)a1[1]; a[6] = (bf16)a1[2]; a[7] = (bf16)a1[3];
#pragma unroll
        for (int n = 0; n < 16; ++n) {
            const bf16x8 b = *(const bf16x8*)(wt + (size_t)(n * 16 + am) * D + kb);
            acc[n] = __builtin_amdgcn_mfma_f32_16x16x32_bf16(a, b, acc[n], 0, 0, 0);
        }
    }

    const int drow = row0 + ag * 4;
#pragma unroll
    for (int r = 0; r < 4; ++r) {
        if (drow + r < NNODES) {
            bf16* hp = h + (size_t)(drow + r) * D + am;
#pragma unroll
            for (int n = 0; n < 16; ++n) hp[n * 16] = (bf16)acc[n][r];
        }
    }
}

// ---------------------------------------------------------------------------
// K2: per-row fused SpMM(bf16 h, ELL) + bias + ELU + LayerNorm + mask-expand
// one wave per row; lane l owns dims [4l, 4l+3]
// ---------------------------------------------------------------------------
__global__ __launch_bounds__(256) void row_kernel(const unsigned short* __restrict__ hb,
                                                  const int* __restrict__ cnt,
                                                  const unsigned long long* __restrict__ ep,
                                                  const float* __restrict__ bias,
                                                  const float* __restrict__ gamma,
                                                  const float* __restrict__ beta,
                                                  const float* __restrict__ mask,
                                                  float* __restrict__ out, int n) {
    const int wave = threadIdx.x >> 6;
    const int lane = threadIdx.x & 63;
    const int r = blockIdx.x * 4 + wave;
    if (r >= n) return;

    const int s = r * ELLW;
    const int e = s + min(cnt[r], ELLW);

    float a0 = 0.f, a1 = 0.f, a2 = 0.f, a3 = 0.f;
    int i = s;
    for (; i + 3 < e; i += 4) {
        const unsigned long long e0 = ep[i], e1 = ep[i + 1], e2 = ep[i + 2], e3 = ep[i + 3];
        const int c0 = (int)(unsigned int)e0, c1 = (int)(unsigned int)e1;
        const int c2 = (int)(unsigned int)e2, c3 = (int)(unsigned int)e3;
        const uint2 q0 = *(const uint2*)(hb + (size_t)c0 * D + lane * 4);
        const uint2 q1 = *(const uint2*)(hb + (size_t)c1 * D + lane * 4);
        const uint2 q2 = *(const uint2*)(hb + (size_t)c2 * D + lane * 4);
        const uint2 q3 = *(const uint2*)(hb + (size_t)c3 * D + lane * 4);
        const float v0 = __uint_as_float((unsigned int)(e0 >> 32));
        const float v1 = __uint_as_float((unsigned int)(e1 >> 32));
        const float v2 = __uint_as_float((unsigned int)(e2 >> 32));
        const float v3 = __uint_as_float((unsigned int)(e3 >> 32));
        a0 += v0 * bflo(q0.x) + v1 * bflo(q1.x) + v2 * bflo(q2.x) + v3 * bflo(q3.x);
        a1 += v0 * bfhi(q0.x) + v1 * bfhi(q1.x) + v2 * bfhi(q2.x) + v3 * bfhi(q3.x);
        a2 += v0 * bflo(q0.y) + v1 * bflo(q1.y) + v2 * bflo(q2.y) + v3 * bflo(q3.y);
        a3 += v0 * bfhi(q0.y) + v1 * bfhi(q1.y) + v2 * bfhi(q2.y) + v3 * bfhi(q3.y);
    }
    for (; i < e; ++i) {
        const unsigned long long e0 = ep[i];
        const int c0 = (int)(unsigned int)e0;
        const uint2 q0 = *(const uint2*)(hb + (size_t)c0 * D + lane * 4);
        const float v0 = __uint_as_float((unsigned int)(e0 >> 32));
        a0 += v0 * bflo(q0.x);
        a1 += v0 * bfhi(q0.x);
        a2 += v0 * bflo(q0.y);
        a3 += v0 * bfhi(q0.y);
    }

    // bias + ELU
    const f32x4 b4 = *(const f32x4*)(bias + lane * 4);
    float x0 = a0 + b4[0], x1 = a1 + b4[1], x2 = a2 + b4[2], x3 = a3 + b4[3];
    x0 = x0 > 0.f ? x0 : expm1f(x0);
    x1 = x1 > 0.f ? x1 : expm1f(x1);
    x2 = x2 > 0.f ? x2 : expm1f(x2);
    x3 = x3 > 0.f ? x3 : expm1f(x3);

    // LayerNorm over 256 dims
    float s1 = x0 + x1 + x2 + x3;
    float s2 = x0 * x0 + x1 * x1 + x2 * x2 + x3 * x3;
#pragma unroll
    for (int d = 1; d < 64; d <<= 1) {
        s1 += __shfl_xor(s1, d);
        s2 += __shfl_xor(s2, d);
    }
    const float mu   = s1 * (1.f / 256.f);
    const float var  = s2 * (1.f / 256.f) - mu * mu;
    const float rsig = rsqrtf(var + LN_EPS);

    const f32x4 g4  = *(const f32x4*)(gamma + lane * 4);
    const f32x4 be4 = *(const f32x4*)(beta + lane * 4);
    const float y0 = (x0 - mu) * rsig * g4[0] + be4[0];
    const float y1 = (x1 - mu) * rsig * g4[1] + be4[1];
    const float y2 = (x2 - mu) * rsig * g4[2] + be4[2];
    const float y3 = (x3 - mu) * rsig * g4[3] + be4[3];

#pragma unroll
    for (int smp = 0; smp < NSAMP; ++smp) {
        const f32x4 m4 = *(const f32x4*)(mask + smp * D + lane * 4);
        f32x4 o;
        o[0] = y0 * m4[0];
        o[1] = y1 * m4[1];
        o[2] = y2 * m4[2];
        o[3] = y3 * m4[3];
        __builtin_nontemporal_store(o, (f32x4*)(out + ((size_t)r * NSAMP + smp) * D + lane * 4));
    }
}

// ---------------------------------------------------------------------------
extern "C" void kernel_launch(void* const* d_in, const int* in_sizes, int n_in,
                              void* d_out, int out_size, void* d_ws, size_t ws_size,
                              hipStream_t stream) {
    const float* x     = (const float*)d_in[0];
    const int*   adj   = (const int*)d_in[1];   // [2][E]: rows then cols
    const float* vals  = (const float*)d_in[2];
    const float* mask  = (const float*)d_in[3];
    const float* w     = (const float*)d_in[4];
    const float* bias  = (const float*)d_in[5];
    const float* gamma = (const float*)d_in[6];
    const float* beta  = (const float*)d_in[7];
    float*       out   = (float*)d_out;

    const int N = NNODES;
    const int E = in_sizes[2];
    const int NBLK = (N + 255) / 256;                 // cnt-zero blocks
    const int GB = (N + 63) / 64;                     // gemm blocks (782)
    const int EB = (E + 256 * EPT - 1) / (256 * EPT); // build blocks (782)

    // workspace layout: 25.6 + 38.4 + 0.125 + 0.2 = 64.33 MB (< 64.6 proven)
    char* ws = (char*)d_ws;
    unsigned short*     hb  = (unsigned short*)ws;                      // 25.6 MB
    unsigned long long* ep  = (unsigned long long*)(hb + (size_t)N * D);// 38.4 MB
    bf16*               wt  = (bf16*)(ep + (size_t)N * ELLW);           // 128 KB
    int*                cnt = (int*)((char*)wt + (size_t)D * D * 2);    // 200 KB

    prep_kernel<<<D + NBLK, 256, 0, stream>>>(w, wt, cnt);
    gemm_build_kernel<<<EB + GB, 256, 0, stream>>>(x, wt, (bf16*)hb,
                                                   adj, adj + E, vals, cnt, ep, EB, E);
    row_kernel<<<(N + 3) / 4, 256, 0, stream>>>(hb, cnt, ep, bias, gamma, beta, mask, out, N);
}

// Round 9
// 254.215 us; speedup vs baseline: 1.4005x; 1.4005x over previous
//
#include <hip/hip_runtime.h>
#include <math.h>

#define NNODES 50000
#define D 256
#define NSAMP 5
#define LN_EPS 1e-5f
#define NB 196           // row buckets of 256 rows: ceil(50000/256)
#define BCAP 9216        // edges per bucket capacity (mean 8163, +11 sigma)
#define ACHUNK 8192      // edges per pass-A block

typedef __bf16 bf16;
typedef __attribute__((ext_vector_type(8))) __bf16 bf16x8;
typedef __attribute__((ext_vector_type(4))) float f32x4;
typedef unsigned long long u64;

__device__ inline float bflo(unsigned int u) { return __uint_as_float(u << 16); }
__device__ inline float bfhi(unsigned int u) { return __uint_as_float(u & 0xffff0000u); }

__device__ inline u64 packrec(int r, int c, float v) {
    // col:16 | row:16 | valbits:32   (N=50000 < 65536 so both fit 16 bits)
    return (u64)(unsigned int)(c | (r << 16)) | ((u64)__float_as_uint(v) << 32);
}

// ---------------------------------------------------------------------------
// K0: blocks 0..255: wt[n][k] = bf16(w[k][n]); block 256: zero bucket cursors
// ---------------------------------------------------------------------------
__global__ void prep_kernel(const float* __restrict__ w, bf16* __restrict__ wt,
                            int* __restrict__ bcur) {
    const int b = blockIdx.x;
    if (b < D) {
        const int k = threadIdx.x;
        wt[(size_t)b * D + k] = (bf16)w[(size_t)k * D + b];
    } else {
        if (threadIdx.x < NB) bcur[threadIdx.x] = 0;
    }
}

// ---------------------------------------------------------------------------
// K1 (fused): blocks [0, AB): pass-A bucket binning (LDS histogram,
//             196 global atomics/block, bucket-contiguous writes)
//             blocks [AB, AB+GB): GEMM h = x @ w via MFMA
// ---------------------------------------------------------------------------
__global__ __launch_bounds__(256) void gemm_binA_kernel(const float* __restrict__ x,
                                                        const bf16* __restrict__ wt,
                                                        bf16* __restrict__ h,
                                                        const int* __restrict__ rows,
                                                        const int* __restrict__ cols,
                                                        const float* __restrict__ vals,
                                                        int* __restrict__ bcur,
                                                        u64* __restrict__ binned,
                                                        int AB, int E) {
    if ((int)blockIdx.x < AB) {
        __shared__ int hist[NB];
        __shared__ int base[NB];
        for (int i = threadIdx.x; i < NB; i += 256) hist[i] = 0;
        __syncthreads();
        const int e0 = blockIdx.x * ACHUNK;
        const int e1 = min(e0 + ACHUNK, E);
        // phase 1: LDS histogram of buckets
        for (int e = e0 + threadIdx.x; e < e1; e += 256)
            atomicAdd(&hist[rows[e] >> 8], 1);
        __syncthreads();
        // phase 2: reserve per-bucket ranges (196 global atomics per block)
        for (int i = threadIdx.x; i < NB; i += 256) {
            const int c = hist[i];
            base[i] = c ? atomicAdd(&bcur[i], c) : 0;
            hist[i] = 0;                      // reuse as local cursor
        }
        __syncthreads();
        // phase 3: scatter edges bucket-contiguously
        for (int e = e0 + threadIdx.x; e < e1; e += 256) {
            const int r = rows[e];
            const int b = r >> 8;
            const int k = base[b] + atomicAdd(&hist[b], 1);
            if (k < BCAP)                     // statistically unreachable guard
                binned[(size_t)b * BCAP + k] = packrec(r, cols[e], vals[e]);
        }
        return;
    }

    // ---- GEMM path (identical to validated round-2 kernel) ----
    const int gb = blockIdx.x - AB;
    const int wave = threadIdx.x >> 6;
    const int lane = threadIdx.x & 63;
    const int row0 = gb * 64 + wave * 16;
    const int am = lane & 15;
    const int ag = lane >> 4;

    int arow = row0 + am;
    if (arow >= NNODES) arow = NNODES - 1;

    f32x4 acc[16];
#pragma unroll
    for (int n = 0; n < 16; ++n) acc[n] = (f32x4){0.f, 0.f, 0.f, 0.f};

#pragma unroll
    for (int kk = 0; kk < 8; ++kk) {
        const int kb = kk * 32 + ag * 8;
        const float* xp = x + (size_t)arow * D + kb;
        const f32x4 a0 = __builtin_nontemporal_load((const f32x4*)xp);
        const f32x4 a1 = __builtin_nontemporal_load((const f32x4*)(xp + 4));
        bf16x8 a;
        a[0] = (bf16)a0[0]; a[1] = (bf16)a0[1]; a[2] = (bf16)a0[2]; a[3] = (bf16)a0[3];
        a[4] = (bf16)a1[0]; a[5] = (bf16)a1[1]; a[6] = (bf16)a1[2]; a[7] = (bf16)a1[3];
#pragma unroll
        for (int n = 0; n < 16; ++n) {
            const bf16x8 b = *(const bf16x8*)(wt + (size_t)(n * 16 + am) * D + kb);
            acc[n] = __builtin_amdgcn_mfma_f32_16x16x32_bf16(a, b, acc[n], 0, 0, 0);
        }
    }

    const int drow = row0 + ag * 4;
#pragma unroll
    for (int r = 0; r < 4; ++r) {
        if (drow + r < NNODES) {
            bf16* hp = h + (size_t)(drow + r) * D + am;
#pragma unroll
            for (int n = 0; n < 16; ++n) hp[n * 16] = (bf16)acc[n][r];
        }
    }
}

// ---------------------------------------------------------------------------
// K2 pass B: one block per bucket — LDS counting sort of the bucket's edges
// into per-bucket CSR segment; emits rstart/rcnt per row.
// ---------------------------------------------------------------------------
__global__ __launch_bounds__(256) void sortB_kernel(const u64* __restrict__ binned,
                                                    const int* __restrict__ bcur,
                                                    u64* __restrict__ sorted,
                                                    int* __restrict__ rstart,
                                                    int* __restrict__ rcnt) {
    const int b = blockIdx.x;
    const int tid = threadIdx.x;
    const int cnt_b = min(bcur[b], BCAP);
    const u64* src = binned + (size_t)b * BCAP;

    __shared__ int hist[256];
    __shared__ int s[256];
    hist[tid] = 0;
    __syncthreads();
    // histogram over the bucket's 256 rows
    for (int i = tid; i < cnt_b; i += 256)
        atomicAdd(&hist[(int)((src[i] >> 16) & 255)], 1);
    __syncthreads();
    // exclusive scan (Hillis-Steele over 256)
    const int v = hist[tid];
    s[tid] = v;
    __syncthreads();
    for (int d = 1; d < 256; d <<= 1) {
        const int t = (tid >= d) ? s[tid - d] : 0;
        __syncthreads();
        s[tid] += t;
        __syncthreads();
    }
    const int excl = s[tid] - v;
    const int r = b * 256 + tid;
    if (r < NNODES) {
        rstart[r] = b * BCAP + excl;
        rcnt[r]   = v;
    }
    hist[tid] = excl;   // reuse as per-row cursor
    __syncthreads();
    // scatter into row-sorted order within the bucket's segment
    for (int i = tid; i < cnt_b; i += 256) {
        const u64 rec = src[i];
        const int k = atomicAdd(&hist[(int)((rec >> 16) & 255)], 1);
        sorted[(size_t)b * BCAP + k] = rec;
    }
}

// ---------------------------------------------------------------------------
// K3: per-row fused SpMM(bf16 h, CSR) + bias + ELU + LayerNorm + mask-expand
// one wave per row; lane l owns dims [4l, 4l+3]
// ---------------------------------------------------------------------------
__global__ __launch_bounds__(256) void row_kernel(const unsigned short* __restrict__ hb,
                                                  const int* __restrict__ rstart,
                                                  const int* __restrict__ rcnt,
                                                  const u64* __restrict__ ep,
                                                  const float* __restrict__ bias,
                                                  const float* __restrict__ gamma,
                                                  const float* __restrict__ beta,
                                                  const float* __restrict__ mask,
                                                  float* __restrict__ out, int n) {
    const int wave = threadIdx.x >> 6;
    const int lane = threadIdx.x & 63;
    const int r = blockIdx.x * 4 + wave;
    if (r >= n) return;

    const int s = rstart[r];
    const int e = s + rcnt[r];

    float a0 = 0.f, a1 = 0.f, a2 = 0.f, a3 = 0.f;
    int i = s;
    for (; i + 3 < e; i += 4) {
        const u64 e0 = ep[i], e1 = ep[i + 1], e2 = ep[i + 2], e3 = ep[i + 3];
        const int c0 = (int)(e0 & 0xFFFF), c1 = (int)(e1 & 0xFFFF);
        const int c2 = (int)(e2 & 0xFFFF), c3 = (int)(e3 & 0xFFFF);
        const uint2 q0 = *(const uint2*)(hb + (size_t)c0 * D + lane * 4);
        const uint2 q1 = *(const uint2*)(hb + (size_t)c1 * D + lane * 4);
        const uint2 q2 = *(const uint2*)(hb + (size_t)c2 * D + lane * 4);
        const uint2 q3 = *(const uint2*)(hb + (size_t)c3 * D + lane * 4);
        const float v0 = __uint_as_float((unsigned int)(e0 >> 32));
        const float v1 = __uint_as_float((unsigned int)(e1 >> 32));
        const float v2 = __uint_as_float((unsigned int)(e2 >> 32));
        const float v3 = __uint_as_float((unsigned int)(e3 >> 32));
        a0 += v0 * bflo(q0.x) + v1 * bflo(q1.x) + v2 * bflo(q2.x) + v3 * bflo(q3.x);
        a1 += v0 * bfhi(q0.x) + v1 * bfhi(q1.x) + v2 * bfhi(q2.x) + v3 * bfhi(q3.x);
        a2 += v0 * bflo(q0.y) + v1 * bflo(q1.y) + v2 * bflo(q2.y) + v3 * bflo(q3.y);
        a3 += v0 * bfhi(q0.y) + v1 * bfhi(q1.y) + v2 * bfhi(q2.y) + v3 * bfhi(q3.y);
    }
    for (; i < e; ++i) {
        const u64 e0 = ep[i];
        const int c0 = (int)(e0 & 0xFFFF);
        const uint2 q0 = *(const uint2*)(hb + (size_t)c0 * D + lane * 4);
        const float v0 = __uint_as_float((unsigned int)(e0 >> 32));
        a0 += v0 * bflo(q0.x);
        a1 += v0 * bfhi(q0.x);
        a2 += v0 * bflo(q0.y);
        a3 += v0 * bfhi(q0.y);
    }

    // bias + ELU
    const f32x4 b4 = *(const f32x4*)(bias + lane * 4);
    float x0 = a0 + b4[0], x1 = a1 + b4[1], x2 = a2 + b4[2], x3 = a3 + b4[3];
    x0 = x0 > 0.f ? x0 : expm1f(x0);
    x1 = x1 > 0.f ? x1 : expm1f(x1);
    x2 = x2 > 0.f ? x2 : expm1f(x2);
    x3 = x3 > 0.f ? x3 : expm1f(x3);

    // LayerNorm over 256 dims
    float s1 = x0 + x1 + x2 + x3;
    float s2 = x0 * x0 + x1 * x1 + x2 * x2 + x3 * x3;
#pragma unroll
    for (int d = 1; d < 64; d <<= 1) {
        s1 += __shfl_xor(s1, d);
        s2 += __shfl_xor(s2, d);
    }
    const float mu   = s1 * (1.f / 256.f);
    const float var  = s2 * (1.f / 256.f) - mu * mu;
    const float rsig = rsqrtf(var + LN_EPS);

    const f32x4 g4  = *(const f32x4*)(gamma + lane * 4);
    const f32x4 be4 = *(const f32x4*)(beta + lane * 4);
    const float y0 = (x0 - mu) * rsig * g4[0] + be4[0];
    const float y1 = (x1 - mu) * rsig * g4[1] + be4[1];
    const float y2 = (x2 - mu) * rsig * g4[2] + be4[2];
    const float y3 = (x3 - mu) * rsig * g4[3] + be4[3];

#pragma unroll
    for (int smp = 0; smp < NSAMP; ++smp) {
        const f32x4 m4 = *(const f32x4*)(mask + smp * D + lane * 4);
        f32x4 o;
        o[0] = y0 * m4[0];
        o[1] = y1 * m4[1];
        o[2] = y2 * m4[2];
        o[3] = y3 * m4[3];
        __builtin_nontemporal_store(o, (f32x4*)(out + ((size_t)r * NSAMP + smp) * D + lane * 4));
    }
}

// ---------------------------------------------------------------------------
extern "C" void kernel_launch(void* const* d_in, const int* in_sizes, int n_in,
                              void* d_out, int out_size, void* d_ws, size_t ws_size,
                              hipStream_t stream) {
    const float* x     = (const float*)d_in[0];
    const int*   adj   = (const int*)d_in[1];   // [2][E]: rows then cols
    const float* vals  = (const float*)d_in[2];
    const float* mask  = (const float*)d_in[3];
    const float* w     = (const float*)d_in[4];
    const float* bias  = (const float*)d_in[5];
    const float* gamma = (const float*)d_in[6];
    const float* beta  = (const float*)d_in[7];
    float*       out   = (float*)d_out;

    const int N = NNODES;
    const int E = in_sizes[2];
    const int GB = (N + 63) / 64;                 // gemm blocks (782)
    const int AB = (E + ACHUNK - 1) / ACHUNK;     // pass-A blocks (196)

    // workspace layout: 25.6 + 14.45 + 14.45 + 0.13 + 0.4 = ~55.0 MB
    char* ws = (char*)d_ws;
    unsigned short* hb     = (unsigned short*)ws;                       // 25.6 MB
    u64*            sorted = (u64*)(hb + (size_t)N * D);                // 14.45 MB
    u64*            binned = sorted + (size_t)NB * BCAP;                // 14.45 MB
    bf16*           wt     = (bf16*)(binned + (size_t)NB * BCAP);       // 128 KB
    int*            bcur   = (int*)((char*)wt + (size_t)D * D * 2);     // 1 KB
    int*            rstart = bcur + 256;                                // 200 KB
    int*            rcnt   = rstart + N;                                // 200 KB

    prep_kernel<<<D + 1, 256, 0, stream>>>(w, wt, bcur);
    gemm_binA_kernel<<<AB + GB, 256, 0, stream>>>(x, wt, (bf16*)hb,
                                                  adj, adj + E, vals, bcur, binned, AB, E);
    sortB_kernel<<<NB, 256, 0, stream>>>(binned, bcur, sorted, rstart, rcnt);
    row_kernel<<<(N + 3) / 4, 256, 0, stream>>>(hb, rstart, rcnt, sorted,
                                                bias, gamma, beta, mask, out, N);
}